// Round 8
// baseline (121.254 us; speedup 1.0000x reference)
//
#include <hip/hip_runtime.h>

#define K_Q   131072
#define B_N   1024
#define D_DIM 128
#define NCLS  10
#define NC2   20
#define NCH   16       // contiguous chunks per row
#define SPAN  8192     // floats per (d,ch) block per queue
#define NEG_INF_F (-1e9f)

// ---------------- kernel 0: zero the atomic counters ----------------
__global__ void k_init(int* cnt, int* accCnt) {
    int t = threadIdx.x;
    if (t < NC2) cnt[t] = 0;
    if (t == 0) *accCnt = 0;
}

// ---------------- kernel 1: per-k class code + class counts ----------------
__global__ void k_code(const int* __restrict__ qp, const int* __restrict__ ql,
                       unsigned char* __restrict__ code, int* __restrict__ cnt) {
    __shared__ int lc[NC2];
    int t = threadIdx.x;
    if (t < NC2) lc[t] = 0;
    __syncthreads();
    int idx = blockIdx.x * blockDim.x + t;
    int stride = gridDim.x * blockDim.x;
    for (int k = idx; k < K_Q; k += stride) {
        int p = qp[k];
        int cd = (p == ql[k]) ? p : (p + NCLS);
        code[k] = (unsigned char)cd;
        atomicAdd(&lc[cd], 1);
    }
    __syncthreads();
    if (t < NC2) atomicAdd(&cnt[t], lc[t]);
}

// -------- kernel 2: streaming + chain-free LDS scatter (ds_add_f32) ---------
// Block (ch, d): reads a contiguous (wrapped) 32-KB span of row d of BOTH
// queues + matching codes. Per element: one ds_add_f32 into the thread's
// private 20-slot LDS accumulator — no RMW chain, no barriers, no
// global_load_lds. 2048 blocks x 20KB = 8 blocks/CU = 32 waves/CU.
__global__ __launch_bounds__(256, 8)
void k_scat(const float* __restrict__ posq, const float* __restrict__ negq,
            const unsigned char* __restrict__ code, float* __restrict__ partial) {
    __shared__ float acc[256 * NC2];   // 20 KB
    const int t  = threadIdx.x;
    const int ch = blockIdx.x;
    const int d  = blockIdx.y;

    float* my = &acc[t * NC2];
#pragma unroll
    for (int j = 0; j < NC2; ++j) my[j] = 0.0f;
    // no sync needed: slots are thread-private until the reduce

    const float4* prow = (const float4*)(posq + (size_t)d * K_Q);
    const float4* nrow = (const float4*)(negq + (size_t)d * K_Q);
    const uchar4* crow = (const uchar4*)code;

    // de-congruenced start phase (float4 units), wrap via mask
    const int s4 = ((ch * SPAN + d * 1664) & (K_Q - 1)) >> 2;

#pragma unroll
    for (int i = 0; i < SPAN / 4 / 256; ++i) {          // 8 iters
        const int idx = (s4 + i * 256 + t) & (K_Q / 4 - 1);
        float4 pv = prow[idx];
        float4 nv = nrow[idx];
        uchar4 cd = crow[idx];
        atomicAdd(&my[cd.x], (cd.x < NCLS) ? pv.x : nv.x);
        atomicAdd(&my[cd.y], (cd.y < NCLS) ? pv.y : nv.y);
        atomicAdd(&my[cd.z], (cd.z < NCLS) ? pv.z : nv.z);
        atomicAdd(&my[cd.w], (cd.w < NCLS) ? pv.w : nv.w);
    }
    __syncthreads();

    // fold 256 -> 64 rows
    if (t < 128) {
#pragma unroll
        for (int j = 0; j < NC2; ++j) acc[t * NC2 + j] += acc[(t + 128) * NC2 + j];
    }
    __syncthreads();
    if (t < 64) {
#pragma unroll
        for (int j = 0; j < NC2; ++j) acc[t * NC2 + j] += acc[(t + 64) * NC2 + j];
    }
    __syncthreads();

    // wave 0: butterfly-reduce 64 rows, write partial[d][ch][20]
    if (t < 64) {
#pragma unroll
        for (int j = 0; j < NC2; ++j) {
            float x = acc[t * NC2 + j];
#pragma unroll
            for (int off = 32; off; off >>= 1) x += __shfl_xor(x, off);
            if (t == 0) partial[((size_t)d * NCH + ch) * NC2 + j] = x;
        }
    }
}

// ---------------- kernel 3: sum chunk partials -> S[20][128] ----------------
__global__ void k_fin(const float* __restrict__ partial, float* __restrict__ S) {
    int idx = blockIdx.x * blockDim.x + threadIdx.x;  // 0..2559
    if (idx >= NC2 * D_DIM) return;
    int j = idx / D_DIM, d = idx % D_DIM;
    float s = 0.0f;
#pragma unroll
    for (int ch = 0; ch < NCH; ++ch)
        s += partial[((size_t)d * NCH + ch) * NC2 + j];
    S[j * D_DIM + d] = s;   // j<10: pos class j; j>=10: neg class j-10
}

// ---------------- kernel 4: per-sample loss ----------------
__global__ void k_loss(const float* __restrict__ q, const int* __restrict__ preds,
                       const float* __restrict__ S, const int* __restrict__ cnt,
                       float* __restrict__ out, int* __restrict__ accCnt) {
    const int b = blockIdx.x;
    const int t = threadIdx.x;  // 128 threads
    const int c = preds[b];

    float qv = q[(size_t)b * D_DIM + t];
    float sp = S[c * D_DIM + t];
    float sn = S[(NCLS + c) * D_DIM + t];
    float s0 = qv * qv, s1 = qv * sp, s2 = qv * sn;

#pragma unroll
    for (int off = 32; off; off >>= 1) {
        s0 += __shfl_xor(s0, off);
        s1 += __shfl_xor(s1, off);
        s2 += __shfl_xor(s2, off);
    }
    __shared__ float red[2][3];
    int wave = t >> 6;
    if ((t & 63) == 0) { red[wave][0] = s0; red[wave][1] = s1; red[wave][2] = s2; }
    __syncthreads();
    if (t == 0) {
        float nq  = red[0][0] + red[1][0];
        float dp  = red[0][1] + red[1][1];
        float dn  = red[0][2] + red[1][2];
        float inv = 1.0f / fmaxf(sqrtf(nq), 1e-12f);
        int cp = cnt[c], cn = cnt[NCLS + c];
        float pl = (cp > 0) ? (dp * inv) / (float)(cp > 1 ? cp : 1) : NEG_INF_F;
        float nl = (cn > 0) ? (dn * inv) / (float)(cn > 1 ? cn : 1) : NEG_INF_F;
        float a  = pl / 0.07f;
        float bb = nl / 0.07f;
        float m  = fmaxf(a, bb);
        float loss = m + logf(expf(a - m) + expf(bb - m)) - a;
        out[b] = loss;
        if (a >= bb) atomicAdd(accCnt, 1);  // argmax ties -> index 0
    }
}

// ---------------- kernel 5: accuracy scalar ----------------
__global__ void k_acc(const int* __restrict__ accCnt, float* __restrict__ out) {
    out[B_N] = (float)(*accCnt) * (1.0f / (float)B_N);
}

extern "C" void kernel_launch(void* const* d_in, const int* in_sizes, int n_in,
                              void* d_out, int out_size, void* d_ws, size_t ws_size,
                              hipStream_t stream) {
    const float* q      = (const float*)d_in[0];
    // d_in[1] = k (unused downstream), d_in[2] = labels (unused)
    const int* preds    = (const int*)d_in[3];
    const float* posq   = (const float*)d_in[4];
    const float* negq   = (const float*)d_in[5];
    const int* qlabels  = (const int*)d_in[6];
    const int* qpreds   = (const int*)d_in[7];
    float* out = (float*)d_out;

    char* ws = (char*)d_ws;
    unsigned char* code = (unsigned char*)ws;           // 131072 B
    int* cnt            = (int*)(ws + 131072);          // 20 ints
    int* accCnt         = (int*)(ws + 131072 + 80);     // 1 int
    float* partial      = (float*)(ws + 131328);        // 2048*20 f32 = 160 KB
    float* S            = (float*)(ws + 131328 + (size_t)D_DIM * NCH * NC2 * 4);

    k_init<<<1, 64, 0, stream>>>(cnt, accCnt);
    k_code<<<256, 256, 0, stream>>>(qpreds, qlabels, code, cnt);
    k_scat<<<dim3(NCH, D_DIM), 256, 0, stream>>>(posq, negq, code, partial);
    k_fin<<<(NC2 * D_DIM + 255) / 256, 256, 0, stream>>>(partial, S);
    k_loss<<<B_N, 128, 0, stream>>>(q, preds, S, cnt, out, accCnt);
    k_acc<<<1, 1, 0, stream>>>(accCnt, out);
}

// Round 9
// 58.942 us; speedup vs baseline: 2.0572x; 2.0572x over previous
//
#include <hip/hip_runtime.h>

#define K_Q   131072
#define B_N   1024
#define D_DIM 128
#define NCLS  10
#define NC2   20
#define KT    64              // k per LDS tile
#define KSPAN 256             // k per block
#define NT    (KSPAN / KT)    // 4 tiles
#define KCH   (K_Q / KSPAN)   // 512 k-chunks
#define RS    (KT + 1)        // LDS row stride (floats)
#define NEG_INF_F (-1e9f)

// ---------------- kernel 0: zero the atomic counters ----------------
__global__ void k_init(int* cnt, int* accCnt) {
    int t = threadIdx.x;
    if (t < NC2) cnt[t] = 0;
    if (t == 0) *accCnt = 0;
}

// ---------------- kernel 1: per-k class code + class counts ----------------
__global__ void k_code(const int* __restrict__ qp, const int* __restrict__ ql,
                       unsigned char* __restrict__ code, int* __restrict__ cnt) {
    __shared__ int lc[NC2];
    int t = threadIdx.x;
    if (t < NC2) lc[t] = 0;
    __syncthreads();
    int idx = blockIdx.x * blockDim.x + t;
    int stride = gridDim.x * blockDim.x;
    for (int k = idx; k < K_Q; k += stride) {
        int p = qp[k];
        int cd = (p == ql[k]) ? p : (p + NCLS);
        code[k] = (unsigned char)cd;
        atomicAdd(&lc[cd], 1);
    }
    __syncthreads();
    if (t < NC2) atomicAdd(&cnt[t], lc[t]);
}

// ------- kernel 2: transposed wave-uniform-code column reduce ----------------
// Block (kch, dhalf, q): 64 d-rows x 256 k of ONE queue. Tiles of 64 k staged
// to LDS [64][65] via regs (issue-early/write-late). Compute: lane = d-row,
// one k per wave-step; code is wave-uniform -> readfirstlane + SCALAR branch
// tree (SALU), ~1 VALU/element total. Pos blocks scalar-skip ~90% of steps.
__global__ __launch_bounds__(256, 6)
void k_t(const float* __restrict__ posq, const float* __restrict__ negq,
         const unsigned char* __restrict__ code, float* __restrict__ partial) {
    __shared__ __align__(16) float buf[64 * RS];     // 16640 B
    __shared__ unsigned cbuf[KSPAN / 4];             // 256 B
    const int t    = threadIdx.x;
    const int wave = t >> 6;
    const int lane = t & 63;
    const int kch  = blockIdx.x;
    const int dh   = blockIdx.y;
    const int q    = blockIdx.z;
    const float* queue = q ? negq : posq;
    const int k0   = kch * KSPAN;
    const int d0   = dh * 64;
    const int r0   = t >> 4;     // 0..15 (staging row group)
    const int col  = t & 15;     // 0..15 (float4 within row)
    const int qoff = q * NCLS;

    if (t < KSPAN / 4) cbuf[t] = ((const unsigned*)code)[k0 / 4 + t];

    float acc[NCLS];
#pragma unroll
    for (int c = 0; c < NCLS; ++c) acc[c] = 0.0f;
    __syncthreads();

    float4 G[4], G2[4];

    // stage-issue for tile tt into R[4]
    auto stage_issue = [&](float4* R, int tt) {
#pragma unroll
        for (int i = 0; i < 4; ++i) {
            bool skip = false;
            if (q == 0) {   // skip float4 whose 4 codes are all neg-class
                unsigned w = cbuf[tt * 16 + col];
                skip = (((w + 0x76767676u) & 0x80808080u) == 0x80808080u);
            }
            const float* src = queue + (size_t)(d0 + i * 16 + r0) * K_Q
                                     + k0 + tt * KT + (col << 2);
            if (skip) { R[i].x = R[i].y = R[i].z = R[i].w = 0.0f; }
            else      { R[i] = *(const float4*)src; }
        }
    };

    stage_issue(G, 0);

    for (int tt = 0; tt < NT; ++tt) {
        // write-late: G -> LDS (banks fully distinct, conflict-free)
#pragma unroll
        for (int i = 0; i < 4; ++i) {
            int rr = i * 16 + r0;
            buf[rr * RS + (col << 2) + 0] = G[i].x;
            buf[rr * RS + (col << 2) + 1] = G[i].y;
            buf[rr * RS + (col << 2) + 2] = G[i].z;
            buf[rr * RS + (col << 2) + 3] = G[i].w;
        }
        __syncthreads();
        if (tt + 1 < NT) stage_issue(G2, tt + 1);   // issue-early next tile

        // compute: wave handles k = wave*16 + s within the tile
#pragma unroll
        for (int s = 0; s < 16; ++s) {
            const int kk = wave * 16 + s;
            unsigned w = cbuf[tt * 16 + (kk >> 2)];
            int sc = (int)((unsigned)__builtin_amdgcn_readfirstlane((int)w)
                           >> ((kk & 3) * 8)) & 0xff;
            int cls = sc - qoff;
            if ((unsigned)cls < (unsigned)NCLS) {
                float v = buf[lane * RS + kk];     // banks (lane+kk)%32: free
                if (cls < 4) {
                    if (cls < 2) { if (cls == 0) acc[0] += v; else acc[1] += v; }
                    else         { if (cls == 2) acc[2] += v; else acc[3] += v; }
                } else if (cls < 8) {
                    if (cls < 6) { if (cls == 4) acc[4] += v; else acc[5] += v; }
                    else         { if (cls == 6) acc[6] += v; else acc[7] += v; }
                } else { if (cls == 8) acc[8] += v; else acc[9] += v; }
            }
        }
        __syncthreads();
#pragma unroll
        for (int i = 0; i < 4; ++i) G[i] = G2[i];
    }

    // epilogue: reduce 4 waves' acc over classes; reuse buf as scratch
    float* red = buf;   // needs 4*10*64 = 2560 floats <= 4160 avail
#pragma unroll
    for (int c = 0; c < NCLS; ++c) red[(wave * NCLS + c) * 64 + lane] = acc[c];
    __syncthreads();
    for (int o = t; o < NCLS * 64; o += 256) {
        int cls = o >> 6, d = o & 63;
        float s = 0.0f;
#pragma unroll
        for (int w = 0; w < 4; ++w) s += red[(w * NCLS + cls) * 64 + d];
        partial[(size_t)((q * 2 + dh) * KCH + kch) * (NCLS * 64) + cls * 64 + d] = s;
    }
}

// ---------------- kernel 3a: sum partials over kch in chunks of 32 ----------
__global__ void k_fin1(const float* __restrict__ partial, float* __restrict__ ws2) {
    int idx = blockIdx.x * blockDim.x + threadIdx.x;   // 0 .. 16*2560-1
    if (idx >= 16 * 4 * NCLS * 64) return;
    int chunk = idx / (4 * NCLS * 64);
    int o     = idx % (4 * NCLS * 64);      // (q*2+dh)*640 + cls*64+d
    int qdh   = o / (NCLS * 64);
    int rem   = o % (NCLS * 64);
    float s = 0.0f;
#pragma unroll 8
    for (int kc = chunk * (KCH / 16); kc < (chunk + 1) * (KCH / 16); ++kc)
        s += partial[(size_t)(qdh * KCH + kc) * (NCLS * 64) + rem];
    ws2[(size_t)chunk * (4 * NCLS * 64) + o] = s;
}

// ---------------- kernel 3b: sum chunks -> S[20][128] ----------------
__global__ void k_fin2(const float* __restrict__ ws2, float* __restrict__ S) {
    int idx = blockIdx.x * blockDim.x + threadIdx.x;   // 0..2559
    if (idx >= 4 * NCLS * 64) return;
    float s = 0.0f;
#pragma unroll
    for (int ch = 0; ch < 16; ++ch)
        s += ws2[(size_t)ch * (4 * NCLS * 64) + idx];
    int qdh = idx / (NCLS * 64);
    int rem = idx % (NCLS * 64);
    int cls = rem / 64, d = rem % 64;
    int q = qdh >> 1, dh = qdh & 1;
    S[(q * NCLS + cls) * D_DIM + dh * 64 + d] = s;
}

// ---------------- kernel 4: per-sample loss ----------------
__global__ void k_loss(const float* __restrict__ q, const int* __restrict__ preds,
                       const float* __restrict__ S, const int* __restrict__ cnt,
                       float* __restrict__ out, int* __restrict__ accCnt) {
    const int b = blockIdx.x;
    const int t = threadIdx.x;  // 128 threads
    const int c = preds[b];

    float qv = q[(size_t)b * D_DIM + t];
    float sp = S[c * D_DIM + t];
    float sn = S[(NCLS + c) * D_DIM + t];
    float s0 = qv * qv, s1 = qv * sp, s2 = qv * sn;

#pragma unroll
    for (int off = 32; off; off >>= 1) {
        s0 += __shfl_xor(s0, off);
        s1 += __shfl_xor(s1, off);
        s2 += __shfl_xor(s2, off);
    }
    __shared__ float red[2][3];
    int wave = t >> 6;
    if ((t & 63) == 0) { red[wave][0] = s0; red[wave][1] = s1; red[wave][2] = s2; }
    __syncthreads();
    if (t == 0) {
        float nq  = red[0][0] + red[1][0];
        float dp  = red[0][1] + red[1][1];
        float dn  = red[0][2] + red[1][2];
        float inv = 1.0f / fmaxf(sqrtf(nq), 1e-12f);
        int cp = cnt[c], cn = cnt[NCLS + c];
        float pl = (cp > 0) ? (dp * inv) / (float)(cp > 1 ? cp : 1) : NEG_INF_F;
        float nl = (cn > 0) ? (dn * inv) / (float)(cn > 1 ? cn : 1) : NEG_INF_F;
        float a  = pl / 0.07f;
        float bb = nl / 0.07f;
        float m  = fmaxf(a, bb);
        float loss = m + logf(expf(a - m) + expf(bb - m)) - a;
        out[b] = loss;
        if (a >= bb) atomicAdd(accCnt, 1);  // argmax ties -> index 0
    }
}

// ---------------- kernel 5: accuracy scalar ----------------
__global__ void k_acc(const int* __restrict__ accCnt, float* __restrict__ out) {
    out[B_N] = (float)(*accCnt) * (1.0f / (float)B_N);
}

extern "C" void kernel_launch(void* const* d_in, const int* in_sizes, int n_in,
                              void* d_out, int out_size, void* d_ws, size_t ws_size,
                              hipStream_t stream) {
    const float* q      = (const float*)d_in[0];
    // d_in[1] = k (unused downstream), d_in[2] = labels (unused)
    const int* preds    = (const int*)d_in[3];
    const float* posq   = (const float*)d_in[4];
    const float* negq   = (const float*)d_in[5];
    const int* qlabels  = (const int*)d_in[6];
    const int* qpreds   = (const int*)d_in[7];
    float* out = (float*)d_out;

    char* ws = (char*)d_ws;
    unsigned char* code = (unsigned char*)ws;           // 131072 B
    int* cnt            = (int*)(ws + 131072);          // 20 ints
    int* accCnt         = (int*)(ws + 131072 + 80);     // 1 int
    float* partial      = (float*)(ws + 131328);        // 2048*640 f32 = 5.24 MB
    float* ws2          = (float*)(ws + 131328 + (size_t)2048 * NCLS * 64 * 4 * 4);
    float* S            = (float*)(ws + 131328 + (size_t)2048 * NCLS * 64 * 4 * 4
                                   + 16 * 4 * NCLS * 64 * 4);

    k_init<<<1, 64, 0, stream>>>(cnt, accCnt);
    k_code<<<256, 256, 0, stream>>>(qpreds, qlabels, code, cnt);
    k_t<<<dim3(KCH, 2, 2), 256, 0, stream>>>(posq, negq, code, partial);
    k_fin1<<<(16 * 4 * NCLS * 64 + 255) / 256, 256, 0, stream>>>(partial, ws2);
    k_fin2<<<(4 * NCLS * 64 + 255) / 256, 256, 0, stream>>>(ws2, S);
    k_loss<<<B_N, 128, 0, stream>>>(q, preds, S, cnt, out, accCnt);
    k_acc<<<1, 1, 0, stream>>>(accCnt, out);
}

// Round 10
// 46.347 us; speedup vs baseline: 2.6162x; 1.2718x over previous
//
#include <hip/hip_runtime.h>

#define K_Q   131072
#define B_N   1024
#define D_DIM 128
#define NCLS  10
#define NC2   20
#define CHUNKS 16
#define NEG_INF_F (-1e9f)

// ---------------- kernel 0: zero counters + accuracy slot ----------------
__global__ void k_init(int* cnt, float* out) {
    int t = threadIdx.x;
    if (t < NC2) cnt[t] = 0;
    if (t == 0) out[B_N] = 0.0f;
}

// ---------------- kernel 1: per-k class code + class counts ----------------
__global__ void k_code(const int* __restrict__ qp, const int* __restrict__ ql,
                       unsigned char* __restrict__ code, int* __restrict__ cnt) {
    __shared__ int lc[NC2];
    int t = threadIdx.x;
    if (t < NC2) lc[t] = 0;
    __syncthreads();
    int idx = blockIdx.x * blockDim.x + t;
    int stride = gridDim.x * blockDim.x;
    for (int k = idx; k < K_Q; k += stride) {
        int p = qp[k];
        int cd = (p == ql[k]) ? p : (p + NCLS);
        code[k] = (unsigned char)cd;
        atomicAdd(&lc[cd], 1);
    }
    __syncthreads();
    if (t < NC2) atomicAdd(&cnt[t], lc[t]);
}

// -------- kernel 2: per-class column sums, LDS-indexed accumulators ---------
// (R3 structure: best measured dispatch 41.8 us = 134 MB / 3.2 TB/s, at the
// per-direction read-delivery ceiling; all pipes idle.)
__global__ __launch_bounds__(256, 4)
void k_reduce(const float* __restrict__ posq, const float* __restrict__ negq,
              const unsigned char* __restrict__ code,
              float* __restrict__ partial) {
    __shared__ float acc[256 * NC2];   // 20 KB: per-thread 20-slot accumulator
    const int d  = blockIdx.y;
    const int ch = blockIdx.x;
    const int t  = threadIdx.x;        // 256 threads
    const int span = K_Q / CHUNKS;     // 8192
    const int k0 = ch * span;

    float* my = &acc[t * NC2];
#pragma unroll
    for (int j = 0; j < NC2; ++j) my[j] = 0.0f;
    __syncthreads();

    const float4* prow = (const float4*)(posq + (size_t)d * K_Q + k0);
    const float4* nrow = (const float4*)(negq + (size_t)d * K_Q + k0);
    const uchar4* crow = (const uchar4*)(code + k0);

    const int iters = span / 4 / 256;  // 8

    // software pipeline: preload iter 0
    float4 pv = prow[t];
    float4 nv = nrow[t];
    uchar4 cd = crow[t];

    for (int it = 0; it < iters; ++it) {
        float4 cpv = pv, cnv = nv;
        uchar4 ccd = cd;
        int nx = (it + 1) * 256 + t;
        if (it + 1 < iters) {           // prefetch next iter before compute
            pv = prow[nx];
            nv = nrow[nx];
            cd = crow[nx];
        }
        {
            int c0 = ccd.x; my[c0] += (c0 < NCLS) ? cpv.x : cnv.x;
            int c1 = ccd.y; my[c1] += (c1 < NCLS) ? cpv.y : cnv.y;
            int c2 = ccd.z; my[c2] += (c2 < NCLS) ? cpv.z : cnv.z;
            int c3 = ccd.w; my[c3] += (c3 < NCLS) ? cpv.w : cnv.w;
        }
    }
    __syncthreads();

    // fold 256 -> 64 thread-rows
    if (t < 128) {
#pragma unroll
        for (int j = 0; j < NC2; ++j) acc[t * NC2 + j] += acc[(t + 128) * NC2 + j];
    }
    __syncthreads();
    if (t < 64) {
#pragma unroll
        for (int j = 0; j < NC2; ++j) acc[t * NC2 + j] += acc[(t + 64) * NC2 + j];
    }
    __syncthreads();

    // wave 0: butterfly-reduce the 64 remaining rows
    if (t < 64) {
        float r[NC2];
#pragma unroll
        for (int j = 0; j < NC2; ++j) {
            float x = acc[t * NC2 + j];
#pragma unroll
            for (int off = 32; off; off >>= 1) x += __shfl_xor(x, off);
            r[j] = x;
        }
        if (t == 0) {
            // layout partial[j][d][ch]: k_loss reads 16 contiguous floats
#pragma unroll
            for (int j = 0; j < NC2; ++j)
                partial[((size_t)j * D_DIM + d) * CHUNKS + ch] = r[j];
        }
    }
}

// ------- kernel 3: per-sample loss (fused chunk-sum + CE + accuracy) --------
__global__ void k_loss(const float* __restrict__ q, const int* __restrict__ preds,
                       const float* __restrict__ partial, const int* __restrict__ cnt,
                       float* __restrict__ out) {
    const int b = blockIdx.x;
    const int t = threadIdx.x;  // 128 threads, t = d
    const int c = preds[b];

    float qv = q[(size_t)b * D_DIM + t];

    // sum the 16 chunk-partials for S_pos[c][t] and S_neg[c][t] (64 B each)
    const float4* pp = (const float4*)(partial + ((size_t)c * D_DIM + t) * CHUNKS);
    const float4* pn = (const float4*)(partial + ((size_t)(c + NCLS) * D_DIM + t) * CHUNKS);
    float sp = 0.f, sn = 0.f;
#pragma unroll
    for (int i = 0; i < 4; ++i) {
        float4 a = pp[i], bq = pn[i];
        sp += a.x + a.y + a.z + a.w;
        sn += bq.x + bq.y + bq.z + bq.w;
    }

    float s0 = qv * qv, s1 = qv * sp, s2 = qv * sn;
#pragma unroll
    for (int off = 32; off; off >>= 1) {
        s0 += __shfl_xor(s0, off);
        s1 += __shfl_xor(s1, off);
        s2 += __shfl_xor(s2, off);
    }
    __shared__ float red[2][3];
    int wave = t >> 6;
    if ((t & 63) == 0) { red[wave][0] = s0; red[wave][1] = s1; red[wave][2] = s2; }
    __syncthreads();
    if (t == 0) {
        float nq  = red[0][0] + red[1][0];
        float dp  = red[0][1] + red[1][1];
        float dn  = red[0][2] + red[1][2];
        float inv = 1.0f / fmaxf(sqrtf(nq), 1e-12f);
        int cp = cnt[c], cn = cnt[NCLS + c];
        float pl = (cp > 0) ? (dp * inv) / (float)(cp > 1 ? cp : 1) : NEG_INF_F;
        float nl = (cn > 0) ? (dn * inv) / (float)(cn > 1 ? cn : 1) : NEG_INF_F;
        float a  = pl / 0.07f;
        float bb = nl / 0.07f;
        float m  = fmaxf(a, bb);
        float loss = m + logf(expf(a - m) + expf(bb - m)) - a;
        out[b] = loss;
        // accuracy: exact multiples of 2^-10 -> order-independent atomic sum
        if (a >= bb) atomicAdd(&out[B_N], 1.0f / (float)B_N);
    }
}

extern "C" void kernel_launch(void* const* d_in, const int* in_sizes, int n_in,
                              void* d_out, int out_size, void* d_ws, size_t ws_size,
                              hipStream_t stream) {
    const float* q      = (const float*)d_in[0];
    // d_in[1] = k (unused downstream), d_in[2] = labels (unused)
    const int* preds    = (const int*)d_in[3];
    const float* posq   = (const float*)d_in[4];
    const float* negq   = (const float*)d_in[5];
    const int* qlabels  = (const int*)d_in[6];
    const int* qpreds   = (const int*)d_in[7];
    float* out = (float*)d_out;

    char* ws = (char*)d_ws;
    unsigned char* code = (unsigned char*)ws;           // 131072 B
    int* cnt            = (int*)(ws + 131072);          // 20 ints
    float* partial      = (float*)(ws + 131328);        // 20*128*16 f32 = 160 KB

    k_init<<<1, 64, 0, stream>>>(cnt, out);
    k_code<<<256, 256, 0, stream>>>(qpreds, qlabels, code, cnt);
    k_reduce<<<dim3(CHUNKS, D_DIM), 256, 0, stream>>>(posq, negq, code, partial);
    k_loss<<<B_N, 128, 0, stream>>>(q, preds, partial, cnt, out);
}